// Round 8
// baseline (236.600 us; speedup 1.0000x reference)
//
#include <hip/hip_runtime.h>

// PAFA loss, MI355X. N=262144 rows, D=256 cols, P=512 patients.
//   within  = sum||x||^2 - sum_p cnt_p*||c_p||^2
//   between = P*sum||c_p||^2 - ||sum_p c_p||^2   (T = sum_p c_p, TT = ||T||^2)
//   gpal    = S2/P - TT/P^2
//   loss    = 0.1*within/(between+1e-6) + 0.1*gpal
//
// Pipeline: memset(8B sync) -> k_sort (fused hist+scan+scatter, 64 blocks,
//           internal device-scope barrier, pids read once, kept in regs)
//           -> k_main (512 blocks x 16 waves, TLP latency hiding)  [R7 proven]
//           -> k_final (tiny).
//
// R5 lesson: never scalarize gather addresses (readlane) -> serial chain.
// R6 lesson: don't fuse heavy tails into k_main -> regalloc ruins hot loop.
// R7 lesson: TLP (32 waves/CU) is the robust latency hider; keep k_main lean.

#define DIMS 256
#define NPAT 512
#define HB 64        // sort blocks
#define HT 1024      // threads per sort block
#define MT 1024      // main threads per block
#define MW 16        // main waves per block

// ws layout (bytes):
//   0      counts  u32[512]
//   2048   starts  u32[512]   (4-aligned padded starts)
//   4096   scalars f32[4] = {SumSq, S1, S2, -}
//   4608   T       f32[256]
//   5632   sync    u32[2] = {ready, scan_done}   (memset to 0 each call)
//   8192   bh      u32[512*64]  [pat][blk] -> exclusive prefix (128 KB)
//   139264 idx     u32[N + 2048]

extern "C" __global__ void __launch_bounds__(HT)
k_sort(const int* __restrict__ pids, int N, unsigned* __restrict__ bh,
       unsigned* __restrict__ counts, unsigned* __restrict__ starts,
       unsigned* __restrict__ idx, float* __restrict__ scalars,
       float* __restrict__ T, unsigned* __restrict__ sync)
{
    __shared__ unsigned h[NPAT];
    __shared__ unsigned tmp[NPAT];
    __shared__ unsigned amLastSh;

    const int t   = threadIdx.x;
    const int blk = blockIdx.x;

    // ---- Phase A: per-block histogram; pids stay in registers ----
    if (t < NPAT) h[t] = 0u;
    __syncthreads();

    const int r = (blk * HT + t) * 4;   // N = HB*HT*4 = 262144 exactly
    int4 p4 = make_int4(-1, -1, -1, -1);
    if (r + 3 < N) {
        p4 = *reinterpret_cast<const int4*>(pids + r);
        atomicAdd(&h[p4.x], 1u);
        atomicAdd(&h[p4.y], 1u);
        atomicAdd(&h[p4.z], 1u);
        atomicAdd(&h[p4.w], 1u);
    } else {
        if (r + 0 < N) { p4.x = pids[r + 0]; atomicAdd(&h[p4.x], 1u); }
        if (r + 1 < N) { p4.y = pids[r + 1]; atomicAdd(&h[p4.y], 1u); }
        if (r + 2 < N) { p4.z = pids[r + 2]; atomicAdd(&h[p4.z], 1u); }
        if (r + 3 < N) { p4.w = pids[r + 3]; atomicAdd(&h[p4.w], 1u); }
    }
    __syncthreads();

    if (t < NPAT)
        __hip_atomic_store(&bh[t * HB + blk], h[t],
                           __ATOMIC_RELEASE, __HIP_MEMORY_SCOPE_AGENT);
    __syncthreads();

    if (t == 0) {
        const unsigned prev = __hip_atomic_fetch_add(
            &sync[0], 1u, __ATOMIC_ACQ_REL, __HIP_MEMORY_SCOPE_AGENT);
        amLastSh = (prev == (unsigned)(HB - 1)) ? 1u : 0u;
    }
    __syncthreads();

    // ---- Phase B: last-arriving block scans; others spin ----
    if (amLastSh) {
        unsigned run = 0u;
        if (t < NPAT) {
            unsigned* rowp = bh + t * HB;
            #pragma unroll
            for (int k = 0; k < HB; k += 4) {
                const unsigned v0 = __hip_atomic_load(rowp + k + 0, __ATOMIC_RELAXED, __HIP_MEMORY_SCOPE_AGENT);
                const unsigned v1 = __hip_atomic_load(rowp + k + 1, __ATOMIC_RELAXED, __HIP_MEMORY_SCOPE_AGENT);
                const unsigned v2 = __hip_atomic_load(rowp + k + 2, __ATOMIC_RELAXED, __HIP_MEMORY_SCOPE_AGENT);
                const unsigned v3 = __hip_atomic_load(rowp + k + 3, __ATOMIC_RELAXED, __HIP_MEMORY_SCOPE_AGENT);
                __hip_atomic_store(rowp + k + 0, run, __ATOMIC_RELAXED, __HIP_MEMORY_SCOPE_AGENT); run += v0;
                __hip_atomic_store(rowp + k + 1, run, __ATOMIC_RELAXED, __HIP_MEMORY_SCOPE_AGENT); run += v1;
                __hip_atomic_store(rowp + k + 2, run, __ATOMIC_RELAXED, __HIP_MEMORY_SCOPE_AGENT); run += v2;
                __hip_atomic_store(rowp + k + 3, run, __ATOMIC_RELAXED, __HIP_MEMORY_SCOPE_AGENT); run += v3;
            }
            counts[t] = run;                    // read by k_main (next dispatch)
            tmp[t] = (run + 3u) & ~3u;          // padded segment
        }
        __syncthreads();
        for (int off = 1; off < NPAT; off <<= 1) {
            const unsigned v = (t >= off && t < NPAT) ? tmp[t - off] : 0u;
            __syncthreads();
            if (t < NPAT) tmp[t] += v;
            __syncthreads();
        }
        if (t < NPAT) {
            const unsigned pad = (run + 3u) & ~3u;
            __hip_atomic_store(&starts[t], tmp[t] - pad,
                               __ATOMIC_RELEASE, __HIP_MEMORY_SCOPE_AGENT);
        }
        if (t < 4)    scalars[t] = 0.0f;        // next-dispatch consumers
        if (t < DIMS) T[t]       = 0.0f;
        __syncthreads();
        if (t == 0)
            __hip_atomic_store(&sync[1], 1u,
                               __ATOMIC_RELEASE, __HIP_MEMORY_SCOPE_AGENT);
    } else {
        if (t == 0) {
            while (__hip_atomic_load(&sync[1], __ATOMIC_ACQUIRE,
                                     __HIP_MEMORY_SCOPE_AGENT) == 0u)
                __builtin_amdgcn_s_sleep(8);
        }
        __syncthreads();
    }

    // ---- Phase C: scatter with precomputed bases (LDS cursors only) ----
    if (t < NPAT) {
        const unsigned st = __hip_atomic_load(&starts[t], __ATOMIC_RELAXED,
                                              __HIP_MEMORY_SCOPE_AGENT);
        const unsigned of = __hip_atomic_load(&bh[t * HB + blk], __ATOMIC_RELAXED,
                                              __HIP_MEMORY_SCOPE_AGENT);
        h[t] = st + of;                         // reuse h as basec
    }
    __syncthreads();

    if (p4.x >= 0) idx[atomicAdd(&h[p4.x], 1u)] = (unsigned)(r + 0);
    if (p4.y >= 0) idx[atomicAdd(&h[p4.y], 1u)] = (unsigned)(r + 1);
    if (p4.z >= 0) idx[atomicAdd(&h[p4.z], 1u)] = (unsigned)(r + 2);
    if (p4.w >= 0) idx[atomicAdd(&h[p4.w], 1u)] = (unsigned)(r + 3);
}

// One block per patient, 16 waves. Wave w handles 4-row batches b = w, w+16,...
// Per batch: one aligned uint4 row-id load, then 4 independent per-lane
// float4 gathers. Latency hidden by 32 waves/CU TLP.   [identical to R7]
extern "C" __global__ void __launch_bounds__(MT, 4)
k_main(const float* __restrict__ feats, const unsigned* __restrict__ idx,
       const unsigned* __restrict__ counts, const unsigned* __restrict__ starts,
       float* __restrict__ T, float* __restrict__ scalars)
{
    __shared__ float part[MW][DIMS];   // 16 KB
    __shared__ float sred[MW];
    __shared__ float cred[4];

    const int p    = blockIdx.x;
    const int lane = threadIdx.x & 63;
    const int w    = threadIdx.x >> 6;        // wave 0..15
    const unsigned start = starts[p];
    const unsigned cnt   = counts[p];
    const unsigned base  = lane * 4;

    float ax = 0.f, ay = 0.f, az = 0.f, aw = 0.f;
    float ssq = 0.f;

    const unsigned nb = cnt >> 2;             // full 4-row batches
    for (unsigned b = (unsigned)w; b < nb; b += MW) {
        const uint4 cid = *reinterpret_cast<const uint4*>(idx + start + 4u * b);
        const float4 v0 = *reinterpret_cast<const float4*>(feats + (size_t)cid.x * DIMS + base);
        const float4 v1 = *reinterpret_cast<const float4*>(feats + (size_t)cid.y * DIMS + base);
        const float4 v2 = *reinterpret_cast<const float4*>(feats + (size_t)cid.z * DIMS + base);
        const float4 v3 = *reinterpret_cast<const float4*>(feats + (size_t)cid.w * DIMS + base);
        ax += v0.x + v1.x + v2.x + v3.x;
        ay += v0.y + v1.y + v2.y + v3.y;
        az += v0.z + v1.z + v2.z + v3.z;
        aw += v0.w + v1.w + v2.w + v3.w;
        ssq += v0.x*v0.x + v0.y*v0.y + v0.z*v0.z + v0.w*v0.w;
        ssq += v1.x*v1.x + v1.y*v1.y + v1.z*v1.z + v1.w*v1.w;
        ssq += v2.x*v2.x + v2.y*v2.y + v2.z*v2.z + v2.w*v2.w;
        ssq += v3.x*v3.x + v3.y*v3.y + v3.z*v3.z + v3.w*v3.w;
    }
    if (w == 0) {   // remainder rows (cnt & 3)
        for (unsigned rr = nb * 4u; rr < cnt; ++rr) {
            const unsigned row = idx[start + rr];
            const float4 v = *reinterpret_cast<const float4*>(feats + (size_t)row * DIMS + base);
            ax += v.x; ay += v.y; az += v.z; aw += v.w;
            ssq += v.x*v.x + v.y*v.y + v.z*v.z + v.w*v.w;
        }
    }

    part[w][base + 0] = ax;
    part[w][base + 1] = ay;
    part[w][base + 2] = az;
    part[w][base + 3] = aw;
    for (int off = 32; off; off >>= 1) ssq += __shfl_down(ssq, off, 64);
    if (lane == 0) sred[w] = ssq;
    __syncthreads();

    const int d = threadIdx.x;
    if (d < DIMS) {
        float s = 0.f;
        #pragma unroll
        for (int ww = 0; ww < MW; ++ww) s += part[ww][d];
        const float cntf = fmaxf((float)cnt, 1.0f);
        const float c = s / cntf;
        atomicAdd(&T[d], c);
        float csq = c * c;
        for (int off = 32; off; off >>= 1) csq += __shfl_down(csq, off, 64);
        if ((d & 63) == 0) cred[d >> 6] = csq;
    }
    __syncthreads();

    if (threadIdx.x == 0) {
        const float s2p = cred[0] + cred[1] + cred[2] + cred[3];
        const float cntf = fmaxf((float)cnt, 1.0f);
        atomicAdd(&scalars[2], s2p);          // S2 += ||c_p||^2
        atomicAdd(&scalars[1], cntf * s2p);   // S1 += cnt_p * ||c_p||^2
        float sq = 0.f;
        #pragma unroll
        for (int ww = 0; ww < MW; ++ww) sq += sred[ww];
        atomicAdd(&scalars[0], sq);           // SumSq
    }
}

extern "C" __global__ void __launch_bounds__(DIMS)
k_final(const float* __restrict__ T, const float* __restrict__ scalars,
        const int* __restrict__ nump, float* __restrict__ out)
{
    __shared__ float red[4];
    const int d = threadIdx.x;
    const float t = T[d];
    float tt = t * t;
    for (int off = 32; off; off >>= 1) tt += __shfl_down(tt, off, 64);
    if ((d & 63) == 0) red[d >> 6] = tt;
    __syncthreads();
    if (d == 0) {
        const double TT    = (double)red[0] + red[1] + red[2] + red[3];
        const double SumSq = (double)scalars[0];
        const double S1    = (double)scalars[1];
        const double S2    = (double)scalars[2];
        const double Pd    = (double)(*nump);
        const double within  = SumSq - S1;
        const double between = Pd * S2 - TT;
        const double pcsl = within / (between + 1e-6);
        const double gpal = S2 / Pd - TT / (Pd * Pd);
        out[0] = (float)(0.1 * pcsl + 0.1 * gpal);
    }
}

extern "C" void kernel_launch(void* const* d_in, const int* in_sizes, int n_in,
                              void* d_out, int out_size, void* d_ws, size_t ws_size,
                              hipStream_t stream)
{
    const float* feats = (const float*)d_in[0];
    const int*   pids  = (const int*)d_in[1];
    const int*   nump  = (const int*)d_in[2];
    float*       out   = (float*)d_out;

    const int N = in_sizes[0] / DIMS;

    char* ws = (char*)d_ws;
    unsigned* counts  = (unsigned*)(ws);
    unsigned* starts  = (unsigned*)(ws + 2048);
    float*    scalars = (float*)(ws + 4096);
    float*    T       = (float*)(ws + 4608);
    unsigned* syncf   = (unsigned*)(ws + 5632);
    unsigned* bh      = (unsigned*)(ws + 8192);
    unsigned* idx     = (unsigned*)(ws + 139264);

    hipMemsetAsync(syncf, 0, 2 * sizeof(unsigned), stream);

    k_sort <<<dim3(HB),   dim3(HT),   0, stream>>>(pids, N, bh, counts, starts,
                                                   idx, scalars, T, syncf);
    k_main <<<dim3(NPAT), dim3(MT),   0, stream>>>(feats, idx, counts, starts,
                                                   T, scalars);
    k_final<<<dim3(1),    dim3(DIMS), 0, stream>>>(T, scalars, nump, out);
}

// Round 9
// 69.326 us; speedup vs baseline: 3.4128x; 3.4128x over previous
//
#include <hip/hip_runtime.h>

// PAFA loss, MI355X. N=262144 rows, D=256 cols, P=512 patients.
//   within  = sum||x||^2 - sum_p cnt_p*||c_p||^2
//   between = P*sum||c_p||^2 - ||sum_p c_p||^2   (T = sum_p c_p, TT = ||T||^2)
//   gpal    = S2/P - TT/P^2
//   loss    = 0.1*within/(between+1e-6) + 0.1*gpal
//
// Pipeline (4 dispatches): hist -> scatter(+per-block scan recompute)
//                          -> main (R7-proven) -> final.
//
// R5 lesson: never scalarize gather addresses (readlane) -> serial chain.
// R6 lesson: don't fuse heavy tails into k_main -> regalloc ruins hot loop.
// R7 lesson: TLP (32 waves/CU) is the robust latency hider; keep k_main lean.
// R8 lesson: dispatch boundaries are far cheaper than device-scope spin
//   barriers (fused k_sort: 184us of coherence traffic to save ~10us of
//   launches). Duplicate tiny work per block instead of synchronizing.

#define DIMS 256
#define NPAT 512
#define HB 64        // hist/scatter blocks
#define HT 1024      // threads per hist/scatter block
#define MT 1024      // main threads per block
#define MW 16        // main waves per block

// ws layout (bytes):
//   0      counts  u32[512]
//   2048   starts  u32[512]   (4-aligned padded starts)
//   4096   scalars f32[4] = {SumSq, S1, S2, -}
//   4608   T       f32[256]
//   8192   bh      u32[512*64]  [pat][blk] raw counts (128 KB)
//   139264 idx     u32[N + 2048]

extern "C" __global__ void __launch_bounds__(HT)
k_hist(const int* __restrict__ pids, int N, unsigned* __restrict__ bh,
       float* __restrict__ scalars, float* __restrict__ T)
{
    __shared__ unsigned h[NPAT];
    const int t = threadIdx.x;
    if (t < NPAT) h[t] = 0u;
    __syncthreads();

    const int r = (blockIdx.x * HT + t) * 4;   // N = HB*HT*4 = 262144 exactly
    if (r + 3 < N) {
        const int4 p4 = *reinterpret_cast<const int4*>(pids + r);
        atomicAdd(&h[p4.x], 1u);
        atomicAdd(&h[p4.y], 1u);
        atomicAdd(&h[p4.z], 1u);
        atomicAdd(&h[p4.w], 1u);
    } else {
        for (int k = 0; k < 4; ++k)
            if (r + k < N) atomicAdd(&h[pids[r + k]], 1u);
    }
    __syncthreads();
    if (t < NPAT) bh[t * HB + blockIdx.x] = h[t];

    if (blockIdx.x == 0) {                 // zero next-dispatch accumulators
        if (t < 4)    scalars[t] = 0.0f;
        if (t < DIMS) T[t]       = 0.0f;
    }
}

// Scatter with per-block scan recompute: thread t reads bh[t][0..63] (L2),
// computes total (-> counts), prefix below own blk, and the block-wide
// padded exclusive scan (-> starts). Placement via LDS cursors only.
extern "C" __global__ void __launch_bounds__(HT)
k_scatter(const int* __restrict__ pids, int N,
          const unsigned* __restrict__ bh, unsigned* __restrict__ counts,
          unsigned* __restrict__ starts, unsigned* __restrict__ idx)
{
    __shared__ unsigned tmp[NPAT];
    __shared__ unsigned basec[NPAT];

    const int t   = threadIdx.x;
    const int blk = blockIdx.x;

    unsigned total = 0u, pref = 0u, padded = 0u;
    if (t < NPAT) {
        const uint4* row = reinterpret_cast<const uint4*>(bh + t * HB);
        #pragma unroll
        for (int k = 0; k < HB / 4; ++k) {
            const uint4 v = row[k];
            const int b0 = 4 * k;
            pref  += (b0 + 0 < blk ? v.x : 0u);
            pref  += (b0 + 1 < blk ? v.y : 0u);
            pref  += (b0 + 2 < blk ? v.z : 0u);
            pref  += (b0 + 3 < blk ? v.w : 0u);
            total += v.x + v.y + v.z + v.w;
        }
        padded = (total + 3u) & ~3u;       // 4-aligned segment
        tmp[t] = padded;
    }
    __syncthreads();
    for (int off = 1; off < NPAT; off <<= 1) {
        const unsigned v = (t >= off && t < NPAT) ? tmp[t - off] : 0u;
        __syncthreads();
        if (t < NPAT) tmp[t] += v;
        __syncthreads();
    }
    if (t < NPAT) {
        const unsigned st = tmp[t] - padded;   // exclusive, 4-aligned
        basec[t] = st + pref;
        if (blk == 0) { starts[t] = st; counts[t] = total; }
    }
    __syncthreads();

    const int r = (blk * HT + t) * 4;
    if (r + 3 < N) {
        const int4 p4 = *reinterpret_cast<const int4*>(pids + r);
        idx[atomicAdd(&basec[p4.x], 1u)] = (unsigned)(r + 0);
        idx[atomicAdd(&basec[p4.y], 1u)] = (unsigned)(r + 1);
        idx[atomicAdd(&basec[p4.z], 1u)] = (unsigned)(r + 2);
        idx[atomicAdd(&basec[p4.w], 1u)] = (unsigned)(r + 3);
    } else {
        for (int k = 0; k < 4; ++k)
            if (r + k < N)
                idx[atomicAdd(&basec[pids[r + k]], 1u)] = (unsigned)(r + k);
    }
}

// One block per patient, 16 waves. Wave w handles 4-row batches b = w, w+16,...
// Per batch: one aligned uint4 row-id load, then 4 independent per-lane
// float4 gathers. Latency hidden by 32 waves/CU TLP.   [identical to R7]
extern "C" __global__ void __launch_bounds__(MT, 4)
k_main(const float* __restrict__ feats, const unsigned* __restrict__ idx,
       const unsigned* __restrict__ counts, const unsigned* __restrict__ starts,
       float* __restrict__ T, float* __restrict__ scalars)
{
    __shared__ float part[MW][DIMS];   // 16 KB
    __shared__ float sred[MW];
    __shared__ float cred[4];

    const int p    = blockIdx.x;
    const int lane = threadIdx.x & 63;
    const int w    = threadIdx.x >> 6;        // wave 0..15
    const unsigned start = starts[p];
    const unsigned cnt   = counts[p];
    const unsigned base  = lane * 4;

    float ax = 0.f, ay = 0.f, az = 0.f, aw = 0.f;
    float ssq = 0.f;

    const unsigned nb = cnt >> 2;             // full 4-row batches
    for (unsigned b = (unsigned)w; b < nb; b += MW) {
        const uint4 cid = *reinterpret_cast<const uint4*>(idx + start + 4u * b);
        const float4 v0 = *reinterpret_cast<const float4*>(feats + (size_t)cid.x * DIMS + base);
        const float4 v1 = *reinterpret_cast<const float4*>(feats + (size_t)cid.y * DIMS + base);
        const float4 v2 = *reinterpret_cast<const float4*>(feats + (size_t)cid.z * DIMS + base);
        const float4 v3 = *reinterpret_cast<const float4*>(feats + (size_t)cid.w * DIMS + base);
        ax += v0.x + v1.x + v2.x + v3.x;
        ay += v0.y + v1.y + v2.y + v3.y;
        az += v0.z + v1.z + v2.z + v3.z;
        aw += v0.w + v1.w + v2.w + v3.w;
        ssq += v0.x*v0.x + v0.y*v0.y + v0.z*v0.z + v0.w*v0.w;
        ssq += v1.x*v1.x + v1.y*v1.y + v1.z*v1.z + v1.w*v1.w;
        ssq += v2.x*v2.x + v2.y*v2.y + v2.z*v2.z + v2.w*v2.w;
        ssq += v3.x*v3.x + v3.y*v3.y + v3.z*v3.z + v3.w*v3.w;
    }
    if (w == 0) {   // remainder rows (cnt & 3)
        for (unsigned rr = nb * 4u; rr < cnt; ++rr) {
            const unsigned row = idx[start + rr];
            const float4 v = *reinterpret_cast<const float4*>(feats + (size_t)row * DIMS + base);
            ax += v.x; ay += v.y; az += v.z; aw += v.w;
            ssq += v.x*v.x + v.y*v.y + v.z*v.z + v.w*v.w;
        }
    }

    part[w][base + 0] = ax;
    part[w][base + 1] = ay;
    part[w][base + 2] = az;
    part[w][base + 3] = aw;
    for (int off = 32; off; off >>= 1) ssq += __shfl_down(ssq, off, 64);
    if (lane == 0) sred[w] = ssq;
    __syncthreads();

    const int d = threadIdx.x;
    if (d < DIMS) {
        float s = 0.f;
        #pragma unroll
        for (int ww = 0; ww < MW; ++ww) s += part[ww][d];
        const float cntf = fmaxf((float)cnt, 1.0f);
        const float c = s / cntf;
        atomicAdd(&T[d], c);
        float csq = c * c;
        for (int off = 32; off; off >>= 1) csq += __shfl_down(csq, off, 64);
        if ((d & 63) == 0) cred[d >> 6] = csq;
    }
    __syncthreads();

    if (threadIdx.x == 0) {
        const float s2p = cred[0] + cred[1] + cred[2] + cred[3];
        const float cntf = fmaxf((float)cnt, 1.0f);
        atomicAdd(&scalars[2], s2p);          // S2 += ||c_p||^2
        atomicAdd(&scalars[1], cntf * s2p);   // S1 += cnt_p * ||c_p||^2
        float sq = 0.f;
        #pragma unroll
        for (int ww = 0; ww < MW; ++ww) sq += sred[ww];
        atomicAdd(&scalars[0], sq);           // SumSq
    }
}

extern "C" __global__ void __launch_bounds__(DIMS)
k_final(const float* __restrict__ T, const float* __restrict__ scalars,
        const int* __restrict__ nump, float* __restrict__ out)
{
    __shared__ float red[4];
    const int d = threadIdx.x;
    const float t = T[d];
    float tt = t * t;
    for (int off = 32; off; off >>= 1) tt += __shfl_down(tt, off, 64);
    if ((d & 63) == 0) red[d >> 6] = tt;
    __syncthreads();
    if (d == 0) {
        const double TT    = (double)red[0] + red[1] + red[2] + red[3];
        const double SumSq = (double)scalars[0];
        const double S1    = (double)scalars[1];
        const double S2    = (double)scalars[2];
        const double Pd    = (double)(*nump);
        const double within  = SumSq - S1;
        const double between = Pd * S2 - TT;
        const double pcsl = within / (between + 1e-6);
        const double gpal = S2 / Pd - TT / (Pd * Pd);
        out[0] = (float)(0.1 * pcsl + 0.1 * gpal);
    }
}

extern "C" void kernel_launch(void* const* d_in, const int* in_sizes, int n_in,
                              void* d_out, int out_size, void* d_ws, size_t ws_size,
                              hipStream_t stream)
{
    const float* feats = (const float*)d_in[0];
    const int*   pids  = (const int*)d_in[1];
    const int*   nump  = (const int*)d_in[2];
    float*       out   = (float*)d_out;

    const int N = in_sizes[0] / DIMS;

    char* ws = (char*)d_ws;
    unsigned* counts  = (unsigned*)(ws);
    unsigned* starts  = (unsigned*)(ws + 2048);
    float*    scalars = (float*)(ws + 4096);
    float*    T       = (float*)(ws + 4608);
    unsigned* bh      = (unsigned*)(ws + 8192);
    unsigned* idx     = (unsigned*)(ws + 139264);

    k_hist   <<<dim3(HB),   dim3(HT),   0, stream>>>(pids, N, bh, scalars, T);
    k_scatter<<<dim3(HB),   dim3(HT),   0, stream>>>(pids, N, bh, counts,
                                                     starts, idx);
    k_main   <<<dim3(NPAT), dim3(MT),   0, stream>>>(feats, idx, counts, starts,
                                                     T, scalars);
    k_final  <<<dim3(1),    dim3(DIMS), 0, stream>>>(T, scalars, nump, out);
}